// Round 3
// baseline (139.185 us; speedup 1.0000x reference)
//
#include <hip/hip_runtime.h>
#include <math.h>

#define N_ROWS 4096
#define K_DIM  2048
#define C_DIM  4096

__device__ __forceinline__ float4 ld4(const float* p) {
    return *reinterpret_cast<const float4*>(p);
}

// ---------------------------------------------------------------------------
// Kernel 1: one wave per row of cov_kernel (2048 rows) + 1 wave for cov_bias.
//   pa[k] = covk[k,:].wa   pb[k] = covk[k,:].wb   cab = {covb.wa, covb.wb}
// Pure wave-shuffle reduction, no LDS, no barriers.
// ---------------------------------------------------------------------------
__global__ __launch_bounds__(256) void k_proj(const float* __restrict__ covk,
                                              const float* __restrict__ covb,
                                              const float* __restrict__ rho,
                                              float* __restrict__ pa,
                                              float* __restrict__ pb,
                                              float* __restrict__ cab) {
    const int w    = (blockIdx.x * 256 + threadIdx.x) >> 6;   // global wave id
    const int lane = threadIdx.x & 63;
    if (w > K_DIM) return;                                     // wave-uniform
    const float* src = (w < K_DIM) ? covk + (size_t)w * C_DIM : covb;
    const float* wa = rho;
    const float* wb = rho + C_DIM;
    float sa = 0.f, sb = 0.f;
#pragma unroll 4
    for (int it = 0; it < 16; ++it) {
        const int j = (it * 64 + lane) * 4;
        float4 c = ld4(src + j);
        float4 a = ld4(wa + j);
        float4 b = ld4(wb + j);
        sa += c.x * a.x + c.y * a.y + c.z * a.z + c.w * a.w;
        sb += c.x * b.x + c.y * b.y + c.z * b.z + c.w * b.w;
    }
#pragma unroll
    for (int off = 32; off > 0; off >>= 1) {
        sa += __shfl_down(sa, off, 64);
        sb += __shfl_down(sb, off, 64);
    }
    if (lane == 0) {
        if (w < K_DIM) { pa[w] = sa; pb[w] = sb; }
        else           { cab[0] = sa; cab[1] = sb; }
    }
}

// ---------------------------------------------------------------------------
// Kernel 2: one wave per row of x (4096 rows). Four fused dot products:
//   u[i] = x[i].pa + ca, v[i] = x[i].pb + cb,
//   out_mu[i] = x[i].muk + mu_bias, d[i] = softplus(x[i].vark + var_bias)+1e-8
// ---------------------------------------------------------------------------
__global__ __launch_bounds__(256) void k_xdots(const float* __restrict__ x,
                                               const float* __restrict__ pa,
                                               const float* __restrict__ pb,
                                               const float* __restrict__ muk,
                                               const float* __restrict__ vark,
                                               const float* __restrict__ cab,
                                               const float* __restrict__ mub,
                                               const float* __restrict__ varb,
                                               float* __restrict__ u,
                                               float* __restrict__ v,
                                               float* __restrict__ dd,
                                               float* __restrict__ out_mu) {
    const int i    = (blockIdx.x * 256 + threadIdx.x) >> 6;   // row = wave id
    const int lane = threadIdx.x & 63;
    const float* xr = x + (size_t)i * K_DIM;
    float s0 = 0.f, s1 = 0.f, s2 = 0.f, s3 = 0.f;
#pragma unroll 2
    for (int it = 0; it < 8; ++it) {
        const int j = (it * 64 + lane) * 4;
        float4 xv = ld4(xr + j);
        float4 a  = ld4(pa + j);
        float4 b  = ld4(pb + j);
        float4 m  = ld4(muk + j);
        float4 wv = ld4(vark + j);
        s0 += xv.x * a.x + xv.y * a.y + xv.z * a.z + xv.w * a.w;
        s1 += xv.x * b.x + xv.y * b.y + xv.z * b.z + xv.w * b.w;
        s2 += xv.x * m.x + xv.y * m.y + xv.z * m.z + xv.w * m.w;
        s3 += xv.x * wv.x + xv.y * wv.y + xv.z * wv.z + xv.w * wv.w;
    }
#pragma unroll
    for (int off = 32; off > 0; off >>= 1) {
        s0 += __shfl_down(s0, off, 64);
        s1 += __shfl_down(s1, off, 64);
        s2 += __shfl_down(s2, off, 64);
        s3 += __shfl_down(s3, off, 64);
    }
    if (lane == 0) {
        u[i] = s0 + cab[0];
        v[i] = s1 + cab[1];
        out_mu[i] = s2 + mub[0];
        float tt = s3 + varb[0];
        float sp = (tt > 20.f) ? tt : log1pf(expf(tt));
        dd[i] = sp + 1e-8f;
    }
}

// ---------------------------------------------------------------------------
// Kernel 3: each block (256 thr) redundantly computes the inclusive prefix
// sums S1 = prefix(v), S2 = prefix(v^2) into LDS (32 KB), then fills 4 rows:
//   out[i,j] = (m+1)*u_i*u_j + (u_i+u_j)*S1[m] + S2[m],  m = min(i,j)
//   out[i,i] = d[i]
// ---------------------------------------------------------------------------
__global__ __launch_bounds__(256, 4) void k_cov(const float* __restrict__ u,
                                                const float* __restrict__ v,
                                                const float* __restrict__ dd,
                                                float* __restrict__ out) {
    __shared__ float sS1[C_DIM];
    __shared__ float sS2[C_DIM];
    __shared__ float tmp[2][256];
    const int t = threadIdx.x;

    // --- per-block scan of v (4096 elems, 16 per thread) ---
    float ve[16], p1[16], p2[16];
#pragma unroll
    for (int g = 0; g < 4; ++g) {
        float4 w = ld4(v + t * 16 + g * 4);
        ve[g * 4 + 0] = w.x; ve[g * 4 + 1] = w.y;
        ve[g * 4 + 2] = w.z; ve[g * 4 + 3] = w.w;
    }
    float r1 = 0.f, r2 = 0.f;
#pragma unroll
    for (int e = 0; e < 16; ++e) {
        r1 += ve[e];         p1[e] = r1;
        r2 += ve[e] * ve[e]; p2[e] = r2;
    }
    tmp[0][t] = r1; tmp[1][t] = r2;
    __syncthreads();
    for (int off = 1; off < 256; off <<= 1) {
        float a1 = (t >= off) ? tmp[0][t - off] : 0.f;
        float a2 = (t >= off) ? tmp[1][t - off] : 0.f;
        __syncthreads();
        tmp[0][t] += a1; tmp[1][t] += a2;
        __syncthreads();
    }
    const float b1 = (t > 0) ? tmp[0][t - 1] : 0.f;
    const float b2 = (t > 0) ? tmp[1][t - 1] : 0.f;
#pragma unroll
    for (int e = 0; e < 16; ++e) {
        sS1[t * 16 + e] = b1 + p1[e];
        sS2[t * 16 + e] = b2 + p2[e];
    }
    __syncthreads();

    // --- fill 4 rows per block ---
    const int i0 = blockIdx.x * 4;
    for (int r = 0; r < 4; ++r) {
        const int i = i0 + r;
        const float ui  = u[i];
        const float s1i = sS1[i];
        const float s2i = sS2[i];
        float* orow = out + ((size_t)i << 12);
#pragma unroll
        for (int c = 0; c < 4; ++c) {
            const int j0 = (c * 256 + t) * 4;
            float4 uj = ld4(u + j0);
            float4 rr;
            if (j0 + 3 < i) {
                // fully below diagonal: m = j
                float4 s1 = *reinterpret_cast<const float4*>(sS1 + j0);
                float4 s2 = *reinterpret_cast<const float4*>(sS2 + j0);
                rr.x = (float)(j0 + 1) * ui * uj.x + (ui + uj.x) * s1.x + s2.x;
                rr.y = (float)(j0 + 2) * ui * uj.y + (ui + uj.y) * s1.y + s2.y;
                rr.z = (float)(j0 + 3) * ui * uj.z + (ui + uj.z) * s1.z + s2.z;
                rr.w = (float)(j0 + 4) * ui * uj.w + (ui + uj.w) * s1.w + s2.w;
            } else if (j0 > i) {
                // fully above diagonal: m = i
                const float mi = (float)(i + 1);
                rr.x = mi * ui * uj.x + (ui + uj.x) * s1i + s2i;
                rr.y = mi * ui * uj.y + (ui + uj.y) * s1i + s2i;
                rr.z = mi * ui * uj.z + (ui + uj.z) * s1i + s2i;
                rr.w = mi * ui * uj.w + (ui + uj.w) * s1i + s2i;
            } else {
                // straddles the diagonal
                const float di = dd[i];
                float uu[4] = {uj.x, uj.y, uj.z, uj.w};
                float re[4];
#pragma unroll
                for (int e = 0; e < 4; ++e) {
                    const int j = j0 + e;
                    if (j < i)
                        re[e] = (float)(j + 1) * ui * uu[e] + (ui + uu[e]) * sS1[j] + sS2[j];
                    else if (j == i)
                        re[e] = di;
                    else
                        re[e] = (float)(i + 1) * ui * uu[e] + (ui + uu[e]) * s1i + s2i;
                }
                rr = make_float4(re[0], re[1], re[2], re[3]);
            }
            *reinterpret_cast<float4*>(orow + j0) = rr;
        }
    }
}

extern "C" void kernel_launch(void* const* d_in, const int* in_sizes, int n_in,
                              void* d_out, int out_size, void* d_ws, size_t ws_size,
                              hipStream_t stream) {
    const float* x    = (const float*)d_in[0];
    const float* muk  = (const float*)d_in[1];
    const float* mub  = (const float*)d_in[2];
    const float* covk = (const float*)d_in[3];
    const float* covb = (const float*)d_in[4];
    const float* vark = (const float*)d_in[5];
    const float* varb = (const float*)d_in[6];
    const float* rho  = (const float*)d_in[7];

    float* out_mu  = (float*)d_out;           // (4096,1) flattened
    float* out_cov = (float*)d_out + N_ROWS;  // (4096,4096)

    float* ws  = (float*)d_ws;
    float* pa  = ws;             // 2048
    float* pb  = pa + K_DIM;     // 2048
    float* cab = pb + K_DIM;     // 2 (padded to 64)
    float* u   = cab + 64;       // 4096
    float* v   = u + C_DIM;      // 4096
    float* dd  = v + C_DIM;      // 4096

    // k1: 2049 waves -> 513 blocks of 4 waves
    hipLaunchKernelGGL(k_proj, dim3(513), dim3(256), 0, stream,
                       covk, covb, rho, pa, pb, cab);
    // k2: 4096 waves -> 1024 blocks
    hipLaunchKernelGGL(k_xdots, dim3(1024), dim3(256), 0, stream,
                       x, pa, pb, muk, vark, cab, mub, varb, u, v, dd, out_mu);
    // k3: 1024 blocks, 4 rows each
    hipLaunchKernelGGL(k_cov, dim3(1024), dim3(256), 0, stream,
                       u, v, dd, out_cov);
}

// Round 4
// 137.316 us; speedup vs baseline: 1.0136x; 1.0136x over previous
//
#include <hip/hip_runtime.h>
#include <math.h>

#define N_ROWS 4096
#define K_DIM  2048
#define C_DIM  4096

__device__ __forceinline__ float4 ld4(const float* p) {
    return *reinterpret_cast<const float4*>(p);
}

// ---------------------------------------------------------------------------
// Kernel 1: TWO waves per row of cov_kernel (better occupancy: 1025 blocks).
//   pa[k] = covk[k,:].wa   pb[k] = covk[k,:].wb   cab = {covb.wa, covb.wb}
// Wave gw = row*2 + half handles columns [half*2048, half*2048+2048).
// The two waves of a row live in the same block; combine via 8-float LDS.
// ---------------------------------------------------------------------------
__global__ __launch_bounds__(256) void k_proj(const float* __restrict__ covk,
                                              const float* __restrict__ covb,
                                              const float* __restrict__ rho,
                                              float* __restrict__ pa,
                                              float* __restrict__ pb,
                                              float* __restrict__ cab) {
    __shared__ float part[2][4];
    const int gw   = (blockIdx.x * 256 + threadIdx.x) >> 6;   // 0..4099
    const int lane = threadIdx.x & 63;
    const int wib  = threadIdx.x >> 6;                        // wave in block
    if (gw < 2 * K_DIM) {
        const int row  = gw >> 1;
        const int half = gw & 1;                              // == wib & 1
        const float* src = covk + (size_t)row * C_DIM + half * 2048;
        const float* a   = rho + half * 2048;
        const float* b   = rho + C_DIM + half * 2048;
        float sa = 0.f, sb = 0.f;
#pragma unroll
        for (int it = 0; it < 8; ++it) {
            const int j = (it * 64 + lane) * 4;
            float4 c  = ld4(src + j);
            float4 av = ld4(a + j);
            float4 bv = ld4(b + j);
            sa += c.x * av.x + c.y * av.y + c.z * av.z + c.w * av.w;
            sb += c.x * bv.x + c.y * bv.y + c.z * bv.z + c.w * bv.w;
        }
#pragma unroll
        for (int off = 32; off > 0; off >>= 1) {
            sa += __shfl_down(sa, off, 64);
            sb += __shfl_down(sb, off, 64);
        }
        if (lane == 0) { part[0][wib] = sa; part[1][wib] = sb; }
        __syncthreads();
        if (lane == 0 && half == 0) {
            pa[row] = part[0][wib] + part[0][wib + 1];
            pb[row] = part[1][wib] + part[1][wib + 1];
        }
    } else if (gw == 2 * K_DIM) {
        // bias row: one wave reads all 4096 of cov_bias
        float sa = 0.f, sb = 0.f;
#pragma unroll 4
        for (int it = 0; it < 16; ++it) {
            const int j = (it * 64 + lane) * 4;
            float4 c  = ld4(covb + j);
            float4 av = ld4(rho + j);
            float4 bv = ld4(rho + C_DIM + j);
            sa += c.x * av.x + c.y * av.y + c.z * av.z + c.w * av.w;
            sb += c.x * bv.x + c.y * bv.y + c.z * bv.z + c.w * bv.w;
        }
#pragma unroll
        for (int off = 32; off > 0; off >>= 1) {
            sa += __shfl_down(sa, off, 64);
            sb += __shfl_down(sb, off, 64);
        }
        if (lane == 0) { cab[0] = sa; cab[1] = sb; }
    }
}

// ---------------------------------------------------------------------------
// Kernel 2: one wave per row of x (4096 rows). Four fused dot products:
//   u[i] = x[i].pa + ca, v[i] = x[i].pb + cb,
//   out_mu[i] = x[i].muk + mu_bias, d[i] = softplus(x[i].vark + var_bias)+1e-8
// ---------------------------------------------------------------------------
__global__ __launch_bounds__(256) void k_xdots(const float* __restrict__ x,
                                               const float* __restrict__ pa,
                                               const float* __restrict__ pb,
                                               const float* __restrict__ muk,
                                               const float* __restrict__ vark,
                                               const float* __restrict__ cab,
                                               const float* __restrict__ mub,
                                               const float* __restrict__ varb,
                                               float* __restrict__ u,
                                               float* __restrict__ v,
                                               float* __restrict__ dd,
                                               float* __restrict__ out_mu) {
    const int i    = (blockIdx.x * 256 + threadIdx.x) >> 6;   // row = wave id
    const int lane = threadIdx.x & 63;
    const float* xr = x + (size_t)i * K_DIM;
    float s0 = 0.f, s1 = 0.f, s2 = 0.f, s3 = 0.f;
#pragma unroll 4
    for (int it = 0; it < 8; ++it) {
        const int j = (it * 64 + lane) * 4;
        float4 xv = ld4(xr + j);
        float4 a  = ld4(pa + j);
        float4 b  = ld4(pb + j);
        float4 m  = ld4(muk + j);
        float4 wv = ld4(vark + j);
        s0 += xv.x * a.x + xv.y * a.y + xv.z * a.z + xv.w * a.w;
        s1 += xv.x * b.x + xv.y * b.y + xv.z * b.z + xv.w * b.w;
        s2 += xv.x * m.x + xv.y * m.y + xv.z * m.z + xv.w * m.w;
        s3 += xv.x * wv.x + xv.y * wv.y + xv.z * wv.z + xv.w * wv.w;
    }
#pragma unroll
    for (int off = 32; off > 0; off >>= 1) {
        s0 += __shfl_down(s0, off, 64);
        s1 += __shfl_down(s1, off, 64);
        s2 += __shfl_down(s2, off, 64);
        s3 += __shfl_down(s3, off, 64);
    }
    if (lane == 0) {
        u[i] = s0 + cab[0];
        v[i] = s1 + cab[1];
        out_mu[i] = s2 + mub[0];
        float tt = s3 + varb[0];
        float sp = (tt > 20.f) ? tt : log1pf(expf(tt));
        dd[i] = sp + 1e-8f;
    }
}

// ---------------------------------------------------------------------------
// Kernel 3: each block (256 thr) redundantly computes the inclusive prefix
// sums S1 = prefix(v), S2 = prefix(v^2) into LDS via shuffle scan (2 barriers),
// then fills 4 output rows:
//   out[i,j] = (m+1)*u_i*u_j + (u_i+u_j)*S1[m] + S2[m],  m = min(i,j)
//   out[i,i] = d[i]
// ---------------------------------------------------------------------------
__global__ __launch_bounds__(256, 4) void k_cov(const float* __restrict__ u,
                                                const float* __restrict__ v,
                                                const float* __restrict__ dd,
                                                float* __restrict__ out) {
    __shared__ float sS1[C_DIM];
    __shared__ float sS2[C_DIM];
    __shared__ float wtot[2][4];
    const int t    = threadIdx.x;
    const int lane = t & 63;
    const int wv   = t >> 6;

    // --- per-thread serial prefix over its 16 contiguous elems ---
    float ve[16], p1[16], p2[16];
#pragma unroll
    for (int g = 0; g < 4; ++g) {
        float4 w = ld4(v + t * 16 + g * 4);
        ve[g * 4 + 0] = w.x; ve[g * 4 + 1] = w.y;
        ve[g * 4 + 2] = w.z; ve[g * 4 + 3] = w.w;
    }
    float r1 = 0.f, r2 = 0.f;
#pragma unroll
    for (int e = 0; e < 16; ++e) {
        r1 += ve[e];         p1[e] = r1;
        r2 += ve[e] * ve[e]; p2[e] = r2;
    }
    // --- wave-level inclusive scan of per-thread totals (shfl_up) ---
    float w1 = r1, w2 = r2;
#pragma unroll
    for (int off = 1; off < 64; off <<= 1) {
        float t1 = __shfl_up(w1, off, 64);
        float t2 = __shfl_up(w2, off, 64);
        if (lane >= off) { w1 += t1; w2 += t2; }
    }
    if (lane == 63) { wtot[0][wv] = w1; wtot[1][wv] = w2; }
    __syncthreads();
    float base1 = 0.f, base2 = 0.f;
    for (int k = 0; k < wv; ++k) { base1 += wtot[0][k]; base2 += wtot[1][k]; }
    const float e1 = base1 + w1 - r1;   // exclusive prefix for this thread
    const float e2 = base2 + w2 - r2;
#pragma unroll
    for (int e = 0; e < 16; ++e) {
        sS1[t * 16 + e] = e1 + p1[e];
        sS2[t * 16 + e] = e2 + p2[e];
    }
    __syncthreads();

    // --- fill 4 rows per block ---
    const int i0 = blockIdx.x * 4;
    for (int r = 0; r < 4; ++r) {
        const int i = i0 + r;
        const float ui  = u[i];
        const float s1i = sS1[i];
        const float s2i = sS2[i];
        float* orow = out + ((size_t)i << 12);
#pragma unroll
        for (int c = 0; c < 4; ++c) {
            const int j0 = (c * 256 + t) * 4;
            float4 uj = ld4(u + j0);
            float4 rr;
            if (j0 + 3 < i) {
                // fully below diagonal: m = j
                float4 s1 = *reinterpret_cast<const float4*>(sS1 + j0);
                float4 s2 = *reinterpret_cast<const float4*>(sS2 + j0);
                rr.x = (float)(j0 + 1) * ui * uj.x + (ui + uj.x) * s1.x + s2.x;
                rr.y = (float)(j0 + 2) * ui * uj.y + (ui + uj.y) * s1.y + s2.y;
                rr.z = (float)(j0 + 3) * ui * uj.z + (ui + uj.z) * s1.z + s2.z;
                rr.w = (float)(j0 + 4) * ui * uj.w + (ui + uj.w) * s1.w + s2.w;
            } else if (j0 > i) {
                // fully above diagonal: m = i
                const float mi = (float)(i + 1);
                rr.x = mi * ui * uj.x + (ui + uj.x) * s1i + s2i;
                rr.y = mi * ui * uj.y + (ui + uj.y) * s1i + s2i;
                rr.z = mi * ui * uj.z + (ui + uj.z) * s1i + s2i;
                rr.w = mi * ui * uj.w + (ui + uj.w) * s1i + s2i;
            } else {
                // straddles the diagonal
                const float di = dd[i];
                float uu[4] = {uj.x, uj.y, uj.z, uj.w};
                float re[4];
#pragma unroll
                for (int e = 0; e < 4; ++e) {
                    const int j = j0 + e;
                    if (j < i)
                        re[e] = (float)(j + 1) * ui * uu[e] + (ui + uu[e]) * sS1[j] + sS2[j];
                    else if (j == i)
                        re[e] = di;
                    else
                        re[e] = (float)(i + 1) * ui * uu[e] + (ui + uu[e]) * s1i + s2i;
                }
                rr = make_float4(re[0], re[1], re[2], re[3]);
            }
            *reinterpret_cast<float4*>(orow + j0) = rr;
        }
    }
}

extern "C" void kernel_launch(void* const* d_in, const int* in_sizes, int n_in,
                              void* d_out, int out_size, void* d_ws, size_t ws_size,
                              hipStream_t stream) {
    const float* x    = (const float*)d_in[0];
    const float* muk  = (const float*)d_in[1];
    const float* mub  = (const float*)d_in[2];
    const float* covk = (const float*)d_in[3];
    const float* covb = (const float*)d_in[4];
    const float* vark = (const float*)d_in[5];
    const float* varb = (const float*)d_in[6];
    const float* rho  = (const float*)d_in[7];

    float* out_mu  = (float*)d_out;           // (4096,1) flattened
    float* out_cov = (float*)d_out + N_ROWS;  // (4096,4096)

    float* ws  = (float*)d_ws;
    float* pa  = ws;             // 2048
    float* pb  = pa + K_DIM;     // 2048
    float* cab = pb + K_DIM;     // 2 (padded to 64)
    float* u   = cab + 64;       // 4096
    float* v   = u + C_DIM;      // 4096
    float* dd  = v + C_DIM;      // 4096

    // k1: 2*2048+1 waves -> 1025 blocks of 4 waves
    hipLaunchKernelGGL(k_proj, dim3(1025), dim3(256), 0, stream,
                       covk, covb, rho, pa, pb, cab);
    // k2: 4096 waves -> 1024 blocks
    hipLaunchKernelGGL(k_xdots, dim3(1024), dim3(256), 0, stream,
                       x, pa, pb, muk, vark, cab, mub, varb, u, v, dd, out_mu);
    // k3: 1024 blocks, 4 rows each
    hipLaunchKernelGGL(k_cov, dim3(1024), dim3(256), 0, stream,
                       u, v, dd, out_cov);
}